// Round 8
// baseline (176.645 us; speedup 1.0000x reference)
//
#include <hip/hip_runtime.h>

// Multi-scale parabolic morphological closing — vertical-scan formulation,
// float4 (4-column) tap loads, LDS-transposed coalesced output.
// closing_k = ero2d(dil2d(x)), W_k = 4<<k, weight(d) = c*(4/W^2)*d^2.
// All 4 separable passes are vertical scans writing transposed:
//   X -dilV-> T1[w][h] -dilH-> T2[h][w] -eroV-> T3[w][h] -eroH-> OUT[h][w]
// Candidate algebra: v -+ cw*(D-pp)^2 = (v -+ cw*D^2) +- (2cw*D)*pp -+ cw*pp^2,
// with tap constants from anchors via literal-multiplier fmas (no carried chains).
// R8 root-cause fix: R3..R7 all plateaued at ~42us/pass because every tap was a
// scalar dword wave-load (256B/instr): ~11.3K wave-loads/CU/pass ~ 19us at the
// L1's ~64B/cy -> VMEM-instruction bound. Each thread now owns 4 consecutive
// fast columns loaded as ONE float4 (1KB/wave-instr): 4x fewer load instrs.

#define HH 256
#define FAST 256
#define BC 32
#define NS 4
#define HW (HH * FAST)
#define SLICE ((long)BC * HW)
#define LSTR 68      // LDS row stride (floats)

#define C4(v, i) ((i) == 0 ? (v).x : (i) == 1 ? (v).y : (i) == 2 ? (v).z : (v).w)

// thread: 4 fast cols (one float4/tap) x 8 slow rows. pb = img + fast base.
template <bool IS_MAX, bool CLAMP>
__device__ __forceinline__ void scan_core4(const float* __restrict__ pb,
                                           int W, float cw, int rowbase,
                                           float res[8][4])
{
    const float PAD = IS_MAX ? -1e30f : 1e30f;
    const float tw = 2.0f * cw;
    const float ss = IS_MAX ? tw : -tw;
    const float q0  = cw * (float)(W * W);        // q at D=-W (and D=+W)
    const float qs0 = cw * (float)(1 - 2 * W);    // cw*(2D+1) at D=-W
    const float qsT = fmaf(tw, (float)W, cw);     // cw*(2W+1) at D=+W
    const float s0  = IS_MAX ? (-tw * (float)W) : (tw * (float)W);
    const float sT  = IS_MAX ? (tw * (float)W) : (-tw * (float)W);

    float acc[8][4];
#pragma unroll
    for (int pp = 0; pp < 8; ++pp)
#pragma unroll
        for (int c = 0; c < 4; ++c) acc[pp][c] = PAD;

    auto load4 = [&](int u) -> float4 {
        const int row = rowbase + u;
        if (!CLAMP) return *(const float4*)(pb + row * FAST);
        const int rc = min(max(row, 0), HH - 1);          // always-safe address
        const float4 t = *(const float4*)(pb + rc * FAST);
        if (row == rc) return t;
        return make_float4(PAD, PAD, PAD, PAD);
    };

    float4 v[8];

    // ---- head: taps t=0..7, tap t valid for pp <= t ----
#pragma unroll
    for (int j = 0; j < 8; ++j) v[j] = load4(j);
#pragma unroll
    for (int j = 0; j < 8; ++j) {
        const float qj = fmaf((float)((j * (j - 1)) / 2), tw, fmaf((float)j, qs0, q0));
        const float sj = fmaf((float)j, ss, s0);
        float vp[4];
#pragma unroll
        for (int c = 0; c < 4; ++c)
            vp[c] = IS_MAX ? C4(v[j], c) - qj : C4(v[j], c) + qj;
#pragma unroll
        for (int pp = 0; pp < 8; ++pp)
            if (pp <= j) {
#pragma unroll
                for (int c = 0; c < 4; ++c) {
                    const float cnd = fmaf(sj, (float)pp, vp[c]);
                    acc[pp][c] = IS_MAX ? fmaxf(acc[pp][c], cnd) : fminf(acc[pp][c], cnd);
                }
            }
    }

    // ---- middle: taps t=8..2W-1 in chunks of 8; nch = W/4-1; guarded unroll ----
    const int nch = (W >> 2) - 1;
#pragma unroll
    for (int m = 0; m < 7; ++m) {
        if (m < nch) {                                    // wave-uniform guard
#pragma unroll
            for (int j = 0; j < 8; ++j) v[j] = load4(8 + 8 * m + j);
#pragma unroll
            for (int j = 0; j < 8; j += 2) {
                const int t0 = 8 + 8 * m + j, t1 = t0 + 1;
                const float qa = fmaf((float)((t0 * (t0 - 1)) / 2), tw,
                                      fmaf((float)t0, qs0, q0));
                const float qb = fmaf((float)((t1 * (t1 - 1)) / 2), tw,
                                      fmaf((float)t1, qs0, q0));
                const float sa = fmaf((float)t0, ss, s0);
                const float sb = fmaf((float)t1, ss, s0);
                float va[4], vb[4];
#pragma unroll
                for (int c = 0; c < 4; ++c) {
                    va[c] = IS_MAX ? C4(v[j], c) - qa     : C4(v[j], c) + qa;
                    vb[c] = IS_MAX ? C4(v[j + 1], c) - qb : C4(v[j + 1], c) + qb;
                }
#pragma unroll
                for (int pp = 0; pp < 8; ++pp)
#pragma unroll
                    for (int c = 0; c < 4; ++c) {
                        const float ca = fmaf(sa, (float)pp, va[c]);
                        const float cb = fmaf(sb, (float)pp, vb[c]);
                        acc[pp][c] = IS_MAX ? fmaxf(acc[pp][c], fmaxf(ca, cb))
                                            : fminf(acc[pp][c], fminf(ca, cb));
                    }
            }
        }
    }

    // ---- tail: taps t=2W+j, j=0..7, valid for pp >= j ----
#pragma unroll
    for (int j = 0; j < 8; ++j) v[j] = load4(2 * W + j);
#pragma unroll
    for (int j = 0; j < 8; ++j) {
        const float qj = fmaf((float)((j * (j - 1)) / 2), tw, fmaf((float)j, qsT, q0));
        const float sj = fmaf((float)j, ss, sT);
        float vp[4];
#pragma unroll
        for (int c = 0; c < 4; ++c)
            vp[c] = IS_MAX ? C4(v[j], c) - qj : C4(v[j], c) + qj;
#pragma unroll
        for (int pp = 0; pp < 8; ++pp)
            if (pp >= j) {
#pragma unroll
                for (int c = 0; c < 4; ++c) {
                    const float cnd = fmaf(sj, (float)pp, vp[c]);
                    acc[pp][c] = IS_MAX ? fmaxf(acc[pp][c], cnd) : fminf(acc[pp][c], cnd);
                }
            }
    }

    // fold -+cw*pp^2
#pragma unroll
    for (int pp = 0; pp < 8; ++pp)
#pragma unroll
        for (int c = 0; c < 4; ++c)
            res[pp][c] = IS_MAX ? fmaf(-cw, (float)(pp * pp), acc[pp][c])
                                : fmaf( cw, (float)(pp * pp), acc[pp][c]);
}

template <bool IS_MAX>
__global__ __launch_bounds__(128, 4) void mscan4(const float* __restrict__ in,
                                                 float* __restrict__ outT,
                                                 const float* __restrict__ cptr,
                                                 long in_ks, long in_zs,
                                                 long out_ks, long out_zs, int kofs)
{
    __shared__ float lds[64 * LSTR];
    const int k = kofs + (int)blockIdx.y;
    const int W = 4 << k;
    const float cw = ldexpf(cptr[0], -(2 + 2 * k));   // c*4/W^2, pow2-exact
    const int tile = blockIdx.x;                      // 16 tiles: 4 fast x 4 slow
    const int x0 = (tile & 3) * 64;                   // fast base
    const int s0 = (tile >> 2) * 64;                  // slow base
    const float* ip = in + (long)k * in_ks + (long)blockIdx.z * in_zs;
    float* op = outT + (long)k * out_ks + (long)blockIdx.z * out_zs;

    const int tid = threadIdx.x;           // 128 threads
    const int txg = tid & 15;              // fast group (4 cols)
    const int ty  = tid >> 4;              // 0..7 slow group (8 rows)
    const int xb  = x0 + 4 * txg;
    const int rowbase = s0 + ty * 8 - W;

    float res[8][4];
    if (rowbase >= 0 && rowbase + 2 * W + 7 < HH)
        scan_core4<IS_MAX, false>(ip + xb, W, cw, rowbase, res);
    else
        scan_core4<IS_MAX, true >(ip + xb, W, cw, rowbase, res);

    // LDS fast-major transpose tile: lds[fastcol][slow] (stride LSTR)
#pragma unroll
    for (int c = 0; c < 4; ++c) {
        float* lp = lds + (4 * txg + c) * LSTR + ty * 8;
        *(float4*)(lp)     = make_float4(res[0][c], res[1][c], res[2][c], res[3][c]);
        *(float4*)(lp + 4) = make_float4(res[4][c], res[5][c], res[6][c], res[7][c]);
    }
    __syncthreads();

    // coalesced store of 64x64 transposed tile: 1024 float4, 8 per thread
#pragma unroll
    for (int p = 0; p < 8; ++p) {
        const int f = p * 128 + tid;
        const int r = f >> 4;              // fast row 0..63
        const int c4 = f & 15;
        const float4 vv = *(const float4*)(lds + r * LSTR + c4 * 4);
        *(float4*)(op + (long)(x0 + r) * FAST + s0 + c4 * 4) = vv;
    }
}

extern "C" void kernel_launch(void* const* d_in, const int* in_sizes, int n_in,
                              void* d_out, int out_size, void* d_ws, size_t ws_size,
                              hipStream_t stream)
{
    const float* x = (const float*)d_in[0];   // [4,8,256,256] fp32
    const float* c = (const float*)d_in[1];   // scalar se_coef
    float* out = (float*)d_out;               // [4,8,4,256,256] fp32
    float* ws  = (float*)d_ws;

    dim3 b(128);
    if (ws_size >= (size_t)(NS * SLICE) * sizeof(float)) {
        // merged: 4 dispatches, all scales in-grid.
        // Rotation: x -> ws(T1) -> out-as-scratch(T2) -> ws(T3) -> out(final).
        dim3 g(16, NS, BC);
        mscan4<true ><<<g, b, 0, stream>>>(x,   ws,  c, 0,     HW, SLICE, HW, 0);
        mscan4<true ><<<g, b, 0, stream>>>(ws,  out, c, SLICE, HW, SLICE, HW, 0);
        mscan4<false><<<g, b, 0, stream>>>(out, ws,  c, SLICE, HW, SLICE, HW, 0);
        mscan4<false><<<g, b, 0, stream>>>(ws,  out, c, SLICE, HW, HW, (long)NS * HW, 0);
    } else {
        // fallback: per-scale ping-pong via one 8.4MB ws slice + out slice k
        dim3 g(16, 1, BC);
        for (int k = 0; k < NS; ++k) {
            float* outk = out + (long)k * HW;
            mscan4<true ><<<g, b, 0, stream>>>(x,    ws,   c, 0, HW, 0, HW, k);
            mscan4<true ><<<g, b, 0, stream>>>(ws,   outk, c, 0, HW, 0, (long)NS * HW, k);
            mscan4<false><<<g, b, 0, stream>>>(outk, ws,   c, 0, (long)NS * HW, 0, HW, k);
            mscan4<false><<<g, b, 0, stream>>>(ws,   outk, c, 0, HW, 0, (long)NS * HW, k);
        }
    }
}